// Round 6
// baseline (593.475 us; speedup 1.0000x reference)
//
#include <hip/hip_runtime.h>

#define N_NODES 100000
#define N_EDGES 3200000
#define CH 256

#define NBUCK 256          // dst >> 9 ; max bucket = 99999>>9 = 195
#define NBUCK_USED 196
#define PBE 4096           // edges per partition block
#define EPT 16             // edges per thread (256 thr)
#define PGRID ((N_EDGES + PBE - 1) / PBE)   // 782

// ---------------- workspace layout (bytes) ----------------
// deg        int[N_NODES]     @ 0          (512 KB)
// off        int[N_NODES]     @ 524288     (512 KB)
// bucket_cnt int[256]         @ 1048576
// bucket_base int[256]        @ 1049600
// bucket_cur int[256]         @ 1050624
// Wtb        ushort[256*256]  @ 1056768    (128 KB)
// edge_src   int[N_EDGES]     @ 1310720    (12.8 MB)
// packed     uint[N_EDGES]    @ 14110720   (12.8 MB)  dead after build_k
// hb         ushort[N*CH]     @ 14110720   (51.2 MB)  ALIASES packed; gemm_h runs after build_k
#define WS_DEG    0
#define WS_OFF    524288
#define WS_BCNT   1048576
#define WS_BBASE  1049600
#define WS_BCUR   1050624
#define WS_WTB    1056768
#define WS_ESRC   1310720
#define WS_PACKED 14110720
#define WS_HB     14110720
#define WS_NEED_H (WS_HB + (size_t)N_NODES * CH * 2)   // 65.3 MB

typedef __bf16  bf16x8 __attribute__((ext_vector_type(8)));
typedef float   f32x4  __attribute__((ext_vector_type(4)));

__device__ __forceinline__ unsigned short f2bf(float f) {
    union { float f; unsigned u; } c; c.f = f;
    unsigned r = c.u + 0x7FFF + ((c.u >> 16) & 1);  // RNE, finite inputs
    return (unsigned short)(r >> 16);
}
__device__ __forceinline__ float bf2f(unsigned short b) {
    union { unsigned u; float f; } c; c.u = (unsigned)b << 16;
    return c.f;
}

// per-block LDS histogram of dst>>9; one global atomic per (block,bin)
__global__ __launch_bounds__(256) void hist_k(const int* __restrict__ dst,
                                              int* __restrict__ bucket_cnt) {
    __shared__ int h[NBUCK];
    int t = threadIdx.x;
    h[t] = 0;
    __syncthreads();
    long e0 = (long)blockIdx.x * PBE;
#pragma unroll
    for (int i = 0; i < EPT; ++i) {
        long e = e0 + i * 256 + t;
        if (e < N_EDGES) atomicAdd(&h[dst[e] >> 9], 1);
    }
    __syncthreads();
    if (h[t]) atomicAdd(&bucket_cnt[t], h[t]);
}

// exclusive scan of 256 bucket counts -> base and cursor
__global__ void bscan_k(const int* __restrict__ cnt, int* __restrict__ base,
                        int* __restrict__ cursor) {
    __shared__ int s[NBUCK];
    int t = threadIdx.x;
    int v0 = cnt[t];
    s[t] = v0;
    __syncthreads();
    for (int st = 1; st < 256; st <<= 1) {
        int v = (t >= st) ? s[t - st] : 0;
        __syncthreads();
        s[t] += v;
        __syncthreads();
    }
    int excl = s[t] - v0;
    base[t] = excl;
    cursor[t] = excl;
}

// rank edges per bucket in LDS, reserve one contiguous global run per
// (block,bucket), write packed (dlow<<17 | src).
__global__ __launch_bounds__(256) void partition_k(const int* __restrict__ src,
                                                   const int* __restrict__ dst,
                                                   int* __restrict__ bucket_cursor,
                                                   unsigned* __restrict__ packed) {
    __shared__ int hist[NBUCK];
    __shared__ int gbase[NBUCK];
    int t = threadIdx.x;
    hist[t] = 0;
    __syncthreads();
    long e0 = (long)blockIdx.x * PBE;
    int b[EPT], rank[EPT];
    unsigned pk[EPT];
#pragma unroll
    for (int i = 0; i < EPT; ++i) {
        long e = e0 + i * 256 + t;
        if (e < N_EDGES) {
            int d = dst[e];
            int s = src[e];
            b[i] = d >> 9;
            pk[i] = ((unsigned)(d & 511) << 17) | (unsigned)s;
            rank[i] = atomicAdd(&hist[b[i]], 1);
        } else b[i] = -1;
    }
    __syncthreads();
    int cnt = hist[t];
    if (cnt > 0) gbase[t] = atomicAdd(&bucket_cursor[t], cnt);
    __syncthreads();
#pragma unroll
    for (int i = 0; i < EPT; ++i)
        if (b[i] >= 0) packed[gbase[b[i]] + rank[i]] = pk[i];
}

// one block per bucket: deg, off (global CSR) and edge_src, zero global atomics.
__global__ __launch_bounds__(256) void build_k(const unsigned* __restrict__ packed,
                                               const int* __restrict__ bucket_base,
                                               const int* __restrict__ bucket_cnt,
                                               int* __restrict__ deg, int* __restrict__ off,
                                               int* __restrict__ edge_src) {
    __shared__ int ldeg[512];
    __shared__ int loff[512];
    __shared__ int lcur[512];
    __shared__ int sscan[256];
    int bk = blockIdx.x;
    int t = threadIdx.x;
    ldeg[t] = 0; ldeg[t + 256] = 0;
    __syncthreads();
    int ebase = bucket_base[bk];
    int ecnt  = bucket_cnt[bk];
    const unsigned* pk = packed + ebase;
    for (int i = t; i < ecnt; i += 256) atomicAdd(&ldeg[pk[i] >> 17], 1);
    __syncthreads();
    int a0 = ldeg[2 * t], a1 = ldeg[2 * t + 1];
    sscan[t] = a0 + a1;
    __syncthreads();
    for (int st = 1; st < 256; st <<= 1) {
        int v = (t >= st) ? sscan[t - st] : 0;
        __syncthreads();
        sscan[t] += v;
        __syncthreads();
    }
    int ex = sscan[t] - (a0 + a1);
    loff[2 * t] = ex;      lcur[2 * t] = ex;
    loff[2 * t + 1] = ex + a0;  lcur[2 * t + 1] = ex + a0;
    __syncthreads();
    int n0 = bk * 512;
#pragma unroll
    for (int j = 0; j < 2; ++j) {
        int dlow = t + j * 256;
        int node = n0 + dlow;
        if (node < N_NODES) {
            deg[node] = ldeg[dlow];
            off[node] = ebase + loff[dlow];
        }
    }
    int* es = edge_src + ebase;
    for (int i = t; i < ecnt; i += 256) {
        unsigned p = pk[i];
        int pos = atomicAdd(&lcur[p >> 17], 1);
        es[pos] = (int)(p & 0x1FFFF);
    }
}

// One wave per node: bitonic-sort the first min(deg,64) entries of the node's
// edge list by src (register shfl network, no LDS). All concurrent aggregate
// waves then sweep hb in ascending-src order together -> L2 locality.
__global__ __launch_bounds__(256) void sort_adj_k(const int* __restrict__ off,
                                                  const int* __restrict__ deg,
                                                  int* __restrict__ edge_src) {
    int wid = threadIdx.x >> 6;
    int lane = threadIdx.x & 63;
    int node = blockIdx.x * 4 + wid;
    int start = off[node];
    int d = deg[node];
    if (d < 2) return;
    int* es = edge_src + start;
    int v = (lane < d) ? es[lane] : 0x7FFFFFFF;
#pragma unroll
    for (int k = 2; k <= 64; k <<= 1) {
#pragma unroll
        for (int j = k >> 1; j > 0; j >>= 1) {
            int p = __shfl_xor(v, j, 64);
            bool dirUp = ((lane & k) == 0);
            bool takeMin = ((lane & j) == 0) ? dirUp : !dirUp;
            int lo = v < p ? v : p;
            int hi = v < p ? p : v;
            v = takeMin ? lo : hi;
        }
    }
    if (lane < d) es[lane] = v;
}

// W[k][n] fp32 -> Wtb[n][k] bf16
__global__ void cast_w_k(const float* __restrict__ W, unsigned short* __restrict__ Wtb) {
    int n = blockIdx.x;
    int k = threadIdx.x;
    Wtb[n * 256 + k] = f2bf(W[k * 256 + n]);
}

// h = x @ W + bias, output bf16. Block: 64 rows x 256 cols, 4 waves.
__global__ __launch_bounds__(256) void gemm_h_k(const float* __restrict__ x,
                                                const unsigned short* __restrict__ Wtb,
                                                const float* __restrict__ bias,
                                                unsigned short* __restrict__ hb) {
    __shared__ unsigned short As[64][264];
    int row0 = blockIdx.x * 64;
    int rows = N_NODES - row0;
    if (rows > 64) rows = 64;
    int tid = threadIdx.x;

#pragma unroll
    for (int i = 0; i < 16; ++i) {
        int f = i * 256 + tid;
        int r = f >> 6;
        int c4 = (f & 63) * 4;
        float4 v = make_float4(0.f, 0.f, 0.f, 0.f);
        if (r < rows)
            v = *reinterpret_cast<const float4*>(x + (size_t)(row0 + r) * CH + c4);
        ushort4 o;
        o.x = f2bf(v.x); o.y = f2bf(v.y); o.z = f2bf(v.z); o.w = f2bf(v.w);
        *reinterpret_cast<ushort4*>(&As[r][c4]) = o;
    }
    __syncthreads();

    int wv = tid >> 6;
    int lane = tid & 63;
    int q = lane >> 4;
    int ln = lane & 15;
    int n0 = wv * 64;

    f32x4 acc[4][4];
#pragma unroll
    for (int mt = 0; mt < 4; ++mt)
#pragma unroll
        for (int nt = 0; nt < 4; ++nt)
            acc[mt][nt] = (f32x4){0.f, 0.f, 0.f, 0.f};

#pragma unroll 2
    for (int kc = 0; kc < 8; ++kc) {
        int koff = kc * 32 + q * 8;
        bf16x8 a[4], b[4];
#pragma unroll
        for (int mt = 0; mt < 4; ++mt)
            a[mt] = *reinterpret_cast<const bf16x8*>(&As[mt * 16 + ln][koff]);
#pragma unroll
        for (int nt = 0; nt < 4; ++nt)
            b[nt] = *reinterpret_cast<const bf16x8*>(Wtb + (size_t)(n0 + nt * 16 + ln) * 256 + koff);
#pragma unroll
        for (int mt = 0; mt < 4; ++mt)
#pragma unroll
            for (int nt = 0; nt < 4; ++nt)
                acc[mt][nt] = __builtin_amdgcn_mfma_f32_16x16x32_bf16(a[mt], b[nt], acc[mt][nt], 0, 0, 0);
    }

    float bv[4];
#pragma unroll
    for (int nt = 0; nt < 4; ++nt) bv[nt] = bias[n0 + nt * 16 + ln];

#pragma unroll
    for (int mt = 0; mt < 4; ++mt) {
#pragma unroll
        for (int r = 0; r < 4; ++r) {
            int row = row0 + mt * 16 + q * 4 + r;
            if (row < N_NODES) {
                unsigned short* po = hb + (size_t)row * CH + n0 + ln;
#pragma unroll
                for (int nt = 0; nt < 4; ++nt)
                    po[nt * 16] = f2bf(acc[mt][nt][r] + bv[nt]);
            }
        }
    }
}

__device__ __forceinline__ void acc8(float* a, uint4 v) {
    union { unsigned u; float f; } t;
    t.u = v.x << 16;          a[0] += t.f;
    t.u = v.x & 0xFFFF0000u;  a[1] += t.f;
    t.u = v.y << 16;          a[2] += t.f;
    t.u = v.y & 0xFFFF0000u;  a[3] += t.f;
    t.u = v.z << 16;          a[4] += t.f;
    t.u = v.z & 0xFFFF0000u;  a[5] += t.f;
    t.u = v.w << 16;          a[6] += t.f;
    t.u = v.w & 0xFFFF0000u;  a[7] += t.f;
}

// out[d] = (sum h[src_e]) / max(deg,1). One wave per node; lanes 0-31 cover
// edge e (16 B/lane over the 512 B row), lanes 32-63 edge e+1 -> 1 KB per
// instruction, 8 edges in flight at 4-deep unroll. fp32 acc[8]/lane, cross-
// half shfl_xor(32) reduce at the end.
__global__ __launch_bounds__(256) void aggregate_h_k(const unsigned short* __restrict__ hb,
                                                     const int* __restrict__ edge_src,
                                                     const int* __restrict__ off,
                                                     const int* __restrict__ deg,
                                                     float* __restrict__ out) {
    int wid = threadIdx.x >> 6;
    int lane = threadIdx.x & 63;
    int node = blockIdx.x * 4 + wid;
    int start = off[node];
    int d = deg[node];
    int h2 = lane >> 5;
    int lr = lane & 31;
    float acc[8];
#pragma unroll
    for (int j = 0; j < 8; ++j) acc[j] = 0.f;
    const int* es = edge_src + start;
    const char* hbase = (const char*)hb + lr * 16;
    int e = 0;
    for (; e + 8 <= d; e += 8) {
        int s[4];
#pragma unroll
        for (int i = 0; i < 4; ++i) s[i] = es[e + 2 * i + h2];
        uint4 v[4];
#pragma unroll
        for (int i = 0; i < 4; ++i)
            v[i] = *reinterpret_cast<const uint4*>(hbase + ((size_t)s[i] << 9));
#pragma unroll
        for (int i = 0; i < 4; ++i) acc8(acc, v[i]);
    }
    for (; e + 2 <= d; e += 2) {
        int s0 = es[e + h2];
        uint4 v = *reinterpret_cast<const uint4*>(hbase + ((size_t)s0 << 9));
        acc8(acc, v);
    }
    if (e < d && h2 == 0) {
        int s0 = es[e];
        uint4 v = *reinterpret_cast<const uint4*>(hbase + ((size_t)s0 << 9));
        acc8(acc, v);
    }
#pragma unroll
    for (int j = 0; j < 8; ++j) acc[j] += __shfl_xor(acc[j], 32, 64);
    float inv = 1.0f / (float)(d > 0 ? d : 1);
    float4 o;
    o.x = acc[h2 * 4 + 0] * inv;
    o.y = acc[h2 * 4 + 1] * inv;
    o.z = acc[h2 * 4 + 2] * inv;
    o.w = acc[h2 * 4 + 3] * inv;
    *reinterpret_cast<float4*>(out + (size_t)node * CH + lr * 8 + h2 * 4) = o;
}

// ---------------- fallback path (ws too small for hb): fp32 aggregate + in-place gemm
__global__ void aggregate_f32_k(const float* __restrict__ x, const int* __restrict__ edge_src,
                                const int* __restrict__ off, const int* __restrict__ deg,
                                float* __restrict__ m) {
    int wid = threadIdx.x >> 6;
    int lane = threadIdx.x & 63;
    int node = blockIdx.x * 4 + wid;
    int start = off[node];
    int d = deg[node];
    float4 acc0 = make_float4(0.f, 0.f, 0.f, 0.f);
    float4 acc1 = make_float4(0.f, 0.f, 0.f, 0.f);
    const float* xb = x + (size_t)lane * 4;
    int e = 0;
    for (; e + 2 <= d; e += 2) {
        int s0 = edge_src[start + e];
        int s1 = edge_src[start + e + 1];
        const float4 v0 = *reinterpret_cast<const float4*>(xb + (size_t)s0 * CH);
        const float4 v1 = *reinterpret_cast<const float4*>(xb + (size_t)s1 * CH);
        acc0.x += v0.x; acc0.y += v0.y; acc0.z += v0.z; acc0.w += v0.w;
        acc1.x += v1.x; acc1.y += v1.y; acc1.z += v1.z; acc1.w += v1.w;
    }
    if (e < d) {
        int s0 = edge_src[start + e];
        const float4 v0 = *reinterpret_cast<const float4*>(xb + (size_t)s0 * CH);
        acc0.x += v0.x; acc0.y += v0.y; acc0.z += v0.z; acc0.w += v0.w;
    }
    acc0.x += acc1.x; acc0.y += acc1.y; acc0.z += acc1.z; acc0.w += acc1.w;
    float inv = 1.0f / (float)(d > 0 ? d : 1);
    acc0.x *= inv; acc0.y *= inv; acc0.z *= inv; acc0.w *= inv;
    *reinterpret_cast<float4*>(m + (size_t)node * CH + lane * 4) = acc0;
}

__global__ __launch_bounds__(256) void gemm_mfma_k(float* __restrict__ io,
                                                   const unsigned short* __restrict__ Wtb,
                                                   const float* __restrict__ bias,
                                                   const int* __restrict__ deg) {
    __shared__ unsigned short As[64][264];
    int row0 = blockIdx.x * 64;
    int rows = N_NODES - row0;
    if (rows > 64) rows = 64;
    int tid = threadIdx.x;
#pragma unroll
    for (int i = 0; i < 16; ++i) {
        int f = i * 256 + tid;
        int r = f >> 6;
        int c4 = (f & 63) * 4;
        float4 v = make_float4(0.f, 0.f, 0.f, 0.f);
        if (r < rows)
            v = *reinterpret_cast<const float4*>(io + (size_t)(row0 + r) * CH + c4);
        ushort4 o;
        o.x = f2bf(v.x); o.y = f2bf(v.y); o.z = f2bf(v.z); o.w = f2bf(v.w);
        *reinterpret_cast<ushort4*>(&As[r][c4]) = o;
    }
    __syncthreads();
    int wv = tid >> 6;
    int lane = tid & 63;
    int q = lane >> 4;
    int ln = lane & 15;
    int n0 = wv * 64;
    f32x4 acc[4][4];
#pragma unroll
    for (int mt = 0; mt < 4; ++mt)
#pragma unroll
        for (int nt = 0; nt < 4; ++nt)
            acc[mt][nt] = (f32x4){0.f, 0.f, 0.f, 0.f};
#pragma unroll 2
    for (int kc = 0; kc < 8; ++kc) {
        int koff = kc * 32 + q * 8;
        bf16x8 a[4], b[4];
#pragma unroll
        for (int mt = 0; mt < 4; ++mt)
            a[mt] = *reinterpret_cast<const bf16x8*>(&As[mt * 16 + ln][koff]);
#pragma unroll
        for (int nt = 0; nt < 4; ++nt)
            b[nt] = *reinterpret_cast<const bf16x8*>(Wtb + (size_t)(n0 + nt * 16 + ln) * 256 + koff);
#pragma unroll
        for (int mt = 0; mt < 4; ++mt)
#pragma unroll
            for (int nt = 0; nt < 4; ++nt)
                acc[mt][nt] = __builtin_amdgcn_mfma_f32_16x16x32_bf16(a[mt], b[nt], acc[mt][nt], 0, 0, 0);
    }
    float bv[4];
#pragma unroll
    for (int nt = 0; nt < 4; ++nt) bv[nt] = bias[n0 + nt * 16 + ln];
#pragma unroll
    for (int mt = 0; mt < 4; ++mt) {
#pragma unroll
        for (int r = 0; r < 4; ++r) {
            int row = row0 + mt * 16 + q * 4 + r;
            if (row < N_NODES) {
                float bon = (deg[row] > 0) ? 1.f : 0.f;
                float* po = io + (size_t)row * CH + n0 + ln;
#pragma unroll
                for (int nt = 0; nt < 4; ++nt)
                    po[nt * 16] = acc[mt][nt][r] + bv[nt] * bon;
            }
        }
    }
}

extern "C" void kernel_launch(void* const* d_in, const int* in_sizes, int n_in,
                              void* d_out, int out_size, void* d_ws, size_t ws_size,
                              hipStream_t stream) {
    const float* x    = (const float*)d_in[0];
    const int*   src  = (const int*)d_in[1];
    const int*   dst  = (const int*)d_in[2];
    const float* W    = (const float*)d_in[3];
    const float* bias = (const float*)d_in[4];
    float* out = (float*)d_out;

    char* ws = (char*)d_ws;
    int* deg        = (int*)(ws + WS_DEG);
    int* off        = (int*)(ws + WS_OFF);
    int* bcnt       = (int*)(ws + WS_BCNT);
    int* bbase      = (int*)(ws + WS_BBASE);
    int* bcur       = (int*)(ws + WS_BCUR);
    unsigned short* Wtb = (unsigned short*)(ws + WS_WTB);
    int* edge_src   = (int*)(ws + WS_ESRC);
    unsigned* packed = (unsigned*)(ws + WS_PACKED);
    unsigned short* hb = (unsigned short*)(ws + WS_HB);  // aliases packed

    bool use_h = ws_size >= WS_NEED_H;

    hipMemsetAsync(bcnt, 0, NBUCK * sizeof(int), stream);

    hist_k<<<PGRID, 256, 0, stream>>>(dst, bcnt);
    bscan_k<<<1, 256, 0, stream>>>(bcnt, bbase, bcur);
    partition_k<<<PGRID, 256, 0, stream>>>(src, dst, bcur, packed);
    build_k<<<NBUCK_USED, 256, 0, stream>>>(packed, bbase, bcnt, deg, off, edge_src);
    sort_adj_k<<<N_NODES / 4, 256, 0, stream>>>(off, deg, edge_src);

    cast_w_k<<<256, 256, 0, stream>>>(W, Wtb);

    if (use_h) {
        gemm_h_k<<<(N_NODES + 63) / 64, 256, 0, stream>>>(x, Wtb, bias, hb);  // after build_k!
        aggregate_h_k<<<N_NODES / 4, 256, 0, stream>>>(hb, edge_src, off, deg, out);
    } else {
        aggregate_f32_k<<<N_NODES / 4, 256, 0, stream>>>(x, edge_src, off, deg, out);
        gemm_mfma_k<<<(N_NODES + 63) / 64, 256, 0, stream>>>(out, Wtb, bias, deg);
    }
}